// Round 1
// 635.431 us; speedup vs baseline: 1.1518x; 1.1518x over previous
//
#include <hip/hip_runtime.h>
#include <hip/hip_bf16.h>

#define NN 2048
#define DD 64

typedef __attribute__((ext_vector_type(8))) short bf16x8;
typedef __attribute__((ext_vector_type(4))) float f32x4;

__device__ __forceinline__ unsigned short f2b(float f) {
    __hip_bfloat16 h = __float2bfloat16(f);
    return __builtin_bit_cast(unsigned short, h);
}

// ---------- prep: q,k -> bf16(2x-1), row-major [bh][n][d] ----------
__global__ void prep_qk(const float4* __restrict__ q, const float4* __restrict__ k,
                        ushort4* __restrict__ qo, ushort4* __restrict__ ko) {
    int i = blockIdx.x * 256 + threadIdx.x;   // exactly (B*H*N*D)/4 threads
    float4 a = q[i], b = k[i];
    ushort4 qa, kb;
    qa.x = f2b(2.f*a.x - 1.f); qa.y = f2b(2.f*a.y - 1.f);
    qa.z = f2b(2.f*a.z - 1.f); qa.w = f2b(2.f*a.w - 1.f);
    kb.x = f2b(2.f*b.x - 1.f); kb.y = f2b(2.f*b.y - 1.f);
    kb.z = f2b(2.f*b.z - 1.f); kb.w = f2b(2.f*b.w - 1.f);
    qo[i] = qa; ko[i] = kb;
}

// ---------- prep: v -> bf16 transposed [bh][d][n] ----------
__global__ void prep_v(const float* __restrict__ v, unsigned short* __restrict__ vt) {
    __shared__ float tile[64][65];
    int bh = blockIdx.x >> 5, jt = blockIdx.x & 31;
    int t = threadIdx.x;
    const float* src = v + ((size_t)bh * NN + jt * 64) * DD;
#pragma unroll
    for (int h = 0; h < 4; ++h) {
        int cc = t + h * 256;            // 1024 float4 chunks
        int row = cc >> 4, c4 = cc & 15;
        float4 f = *(const float4*)(src + row * DD + c4 * 4);
        tile[row][c4*4+0] = f.x; tile[row][c4*4+1] = f.y;
        tile[row][c4*4+2] = f.z; tile[row][c4*4+3] = f.w;
    }
    __syncthreads();
    unsigned short* dst = vt + (size_t)bh * DD * NN + jt * 64;
#pragma unroll
    for (int h = 0; h < 2; ++h) {
        int cc = t + h * 256;            // 512 chunks of 8 bf16
        int d = cc >> 3, c8 = cc & 7;
        unsigned int w0 = (unsigned)f2b(tile[c8*8+0][d]) | ((unsigned)f2b(tile[c8*8+1][d]) << 16);
        unsigned int w1 = (unsigned)f2b(tile[c8*8+2][d]) | ((unsigned)f2b(tile[c8*8+3][d]) << 16);
        unsigned int w2 = (unsigned)f2b(tile[c8*8+4][d]) | ((unsigned)f2b(tile[c8*8+5][d]) << 16);
        unsigned int w3 = (unsigned)f2b(tile[c8*8+6][d]) | ((unsigned)f2b(tile[c8*8+7][d]) << 16);
        uint4 pk = { w0, w1, w2, w3 };
        *(uint4*)(dst + (size_t)d * NN + c8 * 8) = pk;
    }
}

// ---------- fused attention: 512 blocks x 2 Q-tiles, 1 barrier per K-tile ----------
__global__ __launch_bounds__(256, 2) void attn(
        const unsigned short* __restrict__ Qw, const unsigned short* __restrict__ Kw,
        const unsigned short* __restrict__ Vtw,
        float* __restrict__ outp, float* __restrict__ score) {
    __shared__ unsigned short kb[2][64][72];   // K tile, double-buffered
    __shared__ unsigned short vt[2][64][72];   // V^T tile, double-buffered
    __shared__ float sc[4][16][68];            // per-wave f32 score tile (wave-local, no barrier)
    __shared__ float lsum[64];

    const int tid = threadIdx.x;
    const int bh = blockIdx.x & 31, qp = blockIdx.x >> 5;   // XCD-local heads
    const int lane = tid & 63, wave = tid >> 6;
    const int l4 = lane & 15, quad = lane >> 4;
    const int row0 = wave * 16;

    const unsigned short* Kh = Kw + (size_t)bh * NN * DD;
    const unsigned short* Vh = Vtw + (size_t)bh * DD * NN;

    // per-thread staging coords: 512 chunks of 16B over a 64x64 bf16 tile
    const int sr0 = tid >> 3,         sc0 = (tid & 7) * 8;
    const int sr1 = (tid + 256) >> 3, sc1 = ((tid + 256) & 7) * 8;

    for (int it = 0; it < 2; ++it) {
        const int i0 = (qp * 2 + it) * 64;
        const unsigned short* Qh = Qw + ((size_t)bh * NN + i0) * DD;
        float* scoreH = score + (size_t)bh * NN * NN + (size_t)i0 * NN;
        float* outH   = outp  + ((size_t)bh * NN + i0) * DD;

        // ---- Q fragments -> registers (kb[0] as scratch) ----
        {
            uint4 t0 = *(const uint4*)(Qh + (size_t)sr0 * DD + sc0);
            uint4 t1 = *(const uint4*)(Qh + (size_t)sr1 * DD + sc1);
            *(uint4*)&kb[0][sr0][sc0] = t0;
            *(uint4*)&kb[0][sr1][sc1] = t1;
        }
        __syncthreads();
        const bf16x8 a0 = *(const bf16x8*)&kb[0][row0 + l4][quad * 8];
        const bf16x8 a1 = *(const bf16x8*)&kb[0][row0 + l4][32 + quad * 8];
        __syncthreads();

        // ================= phase 1: softmax denominators =================
        uint4 k0 = *(const uint4*)(Kh + (size_t)sr0 * DD + sc0);
        uint4 k1 = *(const uint4*)(Kh + (size_t)sr1 * DD + sc1);
        *(uint4*)&kb[0][sr0][sc0] = k0;
        *(uint4*)&kb[0][sr1][sc1] = k1;
        k0 = *(const uint4*)(Kh + (size_t)64 * DD + (size_t)sr0 * DD + sc0);
        k1 = *(const uint4*)(Kh + (size_t)64 * DD + (size_t)sr1 * DD + sc1);
        __syncthreads();

        float psum[4] = {0.f, 0.f, 0.f, 0.f};
        for (int kt = 0; kt < 32; ++kt) {
            const int cur = kt & 1, nxt = cur ^ 1;
            if (kt + 1 < 32) {                      // write tile kt+1 (regs -> LDS)
                *(uint4*)&kb[nxt][sr0][sc0] = k0;
                *(uint4*)&kb[nxt][sr1][sc1] = k1;
            }
            if (kt + 2 < 32) {                      // prefetch tile kt+2 (hidden under compute)
                const unsigned short* s = Kh + (size_t)(kt + 2) * 64 * DD;
                k0 = *(const uint4*)(s + (size_t)sr0 * DD + sc0);
                k1 = *(const uint4*)(s + (size_t)sr1 * DD + sc1);
            }
#pragma unroll
            for (int nb = 0; nb < 4; ++nb) {
                bf16x8 b0 = *(const bf16x8*)&kb[cur][nb * 16 + l4][quad * 8];
                bf16x8 b1 = *(const bf16x8*)&kb[cur][nb * 16 + l4][32 + quad * 8];
                f32x4 acc = {0.f, 0.f, 0.f, 0.f};
                acc = __builtin_amdgcn_mfma_f32_16x16x32_bf16(a0, b0, acc, 0, 0, 0);
                acc = __builtin_amdgcn_mfma_f32_16x16x32_bf16(a1, b1, acc, 0, 0, 0);
#pragma unroll
                for (int r = 0; r < 4; ++r)
                    psum[r] += __expf(fmaf(acc[r], 0.0078125f, 0.5f));
            }
            __syncthreads();                        // single barrier per K-tile
        }
#pragma unroll
        for (int r = 0; r < 4; ++r) {
#pragma unroll
            for (int m = 1; m < 16; m <<= 1) psum[r] += __shfl_xor(psum[r], m, 64);
        }
        if (l4 == 0) {
#pragma unroll
            for (int r = 0; r < 4; ++r) lsum[row0 + quad * 4 + r] = psum[r];
        }

        // ================= phase 2: score + O = P*V =================
        uint4 w0, w1;
        k0 = *(const uint4*)(Kh + (size_t)sr0 * DD + sc0);
        k1 = *(const uint4*)(Kh + (size_t)sr1 * DD + sc1);
        w0 = *(const uint4*)(Vh + (size_t)sr0 * NN + sc0);
        w1 = *(const uint4*)(Vh + (size_t)sr1 * NN + sc1);
        *(uint4*)&kb[0][sr0][sc0] = k0;
        *(uint4*)&kb[0][sr1][sc1] = k1;
        *(uint4*)&vt[0][sr0][sc0] = w0;
        *(uint4*)&vt[0][sr1][sc1] = w1;
        k0 = *(const uint4*)(Kh + (size_t)64 * DD + (size_t)sr0 * DD + sc0);
        k1 = *(const uint4*)(Kh + (size_t)64 * DD + (size_t)sr1 * DD + sc1);
        w0 = *(const uint4*)(Vh + 64 + (size_t)sr0 * NN + sc0);
        w1 = *(const uint4*)(Vh + 64 + (size_t)sr1 * NN + sc1);
        __syncthreads();                            // lsum + tile0 visible

        float rinv[4];
#pragma unroll
        for (int r = 0; r < 4; ++r) rinv[r] = 1.0f / lsum[row0 + quad * 4 + r];
        f32x4 o[4];
#pragma unroll
        for (int nb = 0; nb < 4; ++nb) o[nb] = (f32x4){0.f, 0.f, 0.f, 0.f};

        for (int kt = 0; kt < 32; ++kt) {
            const int cur = kt & 1, nxt = cur ^ 1;
            // deferred score writeback of tile kt-1: 256B contiguous per row,
            // store acks drain at the NEXT barrier (hidden under this tile's compute)
            if (kt > 0) {
#pragma unroll
                for (int h = 0; h < 4; ++h) {
                    const int rr = h * 4 + quad;
                    f32x4 wv = *(const f32x4*)&sc[wave][rr][l4 * 4];
                    __builtin_nontemporal_store(wv,
                        (f32x4*)&scoreH[(size_t)(row0 + rr) * NN + (kt - 1) * 64 + l4 * 4]);
                }
            }
            if (kt + 1 < 32) {
                *(uint4*)&kb[nxt][sr0][sc0] = k0;
                *(uint4*)&kb[nxt][sr1][sc1] = k1;
                *(uint4*)&vt[nxt][sr0][sc0] = w0;
                *(uint4*)&vt[nxt][sr1][sc1] = w1;
            }
            if (kt + 2 < 32) {
                const unsigned short* sk = Kh + (size_t)(kt + 2) * 64 * DD;
                const unsigned short* sv = Vh + (size_t)(kt + 2) * 64;
                k0 = *(const uint4*)(sk + (size_t)sr0 * DD + sc0);
                k1 = *(const uint4*)(sk + (size_t)sr1 * DD + sc1);
                w0 = *(const uint4*)(sv + (size_t)sr0 * NN + sc0);
                w1 = *(const uint4*)(sv + (size_t)sr1 * NN + sc1);
            }
            // QK^T + softmax -> per-wave f32 tile in LDS
#pragma unroll
            for (int nb = 0; nb < 4; ++nb) {
                bf16x8 b0 = *(const bf16x8*)&kb[cur][nb * 16 + l4][quad * 8];
                bf16x8 b1 = *(const bf16x8*)&kb[cur][nb * 16 + l4][32 + quad * 8];
                f32x4 acc = {0.f, 0.f, 0.f, 0.f};
                acc = __builtin_amdgcn_mfma_f32_16x16x32_bf16(a0, b0, acc, 0, 0, 0);
                acc = __builtin_amdgcn_mfma_f32_16x16x32_bf16(a1, b1, acc, 0, 0, 0);
#pragma unroll
                for (int r = 0; r < 4; ++r) {
                    float p = __expf(fmaf(acc[r], 0.0078125f, 0.5f)) * rinv[r];
                    sc[wave][quad * 4 + r][nb * 16 + l4] = p;
                }
            }
            // P fragments from sc (same-wave DS ordering; no barrier)
            f32x4 x0 = *(const f32x4*)&sc[wave][l4][quad * 8];
            f32x4 x1 = *(const f32x4*)&sc[wave][l4][quad * 8 + 4];
            f32x4 y0 = *(const f32x4*)&sc[wave][l4][32 + quad * 8];
            f32x4 y1 = *(const f32x4*)&sc[wave][l4][32 + quad * 8 + 4];
            bf16x8 p0, p1;
#pragma unroll
            for (int j = 0; j < 4; ++j) {
                p0[j]     = (short)f2b(x0[j]);
                p0[j + 4] = (short)f2b(x1[j]);
                p1[j]     = (short)f2b(y0[j]);
                p1[j + 4] = (short)f2b(y1[j]);
            }
#pragma unroll
            for (int nb = 0; nb < 4; ++nb) {
                bf16x8 u0 = *(const bf16x8*)&vt[cur][nb * 16 + l4][quad * 8];
                bf16x8 u1 = *(const bf16x8*)&vt[cur][nb * 16 + l4][32 + quad * 8];
                o[nb] = __builtin_amdgcn_mfma_f32_16x16x32_bf16(p0, u0, o[nb], 0, 0, 0);
                o[nb] = __builtin_amdgcn_mfma_f32_16x16x32_bf16(p1, u1, o[nb], 0, 0, 0);
            }
            __syncthreads();                        // single barrier per K-tile
        }
        // final score tile (kt = 31)
#pragma unroll
        for (int h = 0; h < 4; ++h) {
            const int rr = h * 4 + quad;
            f32x4 wv = *(const f32x4*)&sc[wave][rr][l4 * 4];
            __builtin_nontemporal_store(wv,
                (f32x4*)&scoreH[(size_t)(row0 + rr) * NN + 31 * 64 + l4 * 4]);
        }
        // out through sc for contiguous 16-row stores (wave-local)
#pragma unroll
        for (int nb = 0; nb < 4; ++nb)
#pragma unroll
            for (int r = 0; r < 4; ++r)
                sc[wave][quad * 4 + r][nb * 16 + l4] = o[nb][r];
#pragma unroll
        for (int h = 0; h < 4; ++h) {
            const int rr = h * 4 + quad;
            f32x4 wv = *(const f32x4*)&sc[wave][rr][l4 * 4];
            *(f32x4*)&outH[(size_t)(row0 + rr) * DD + l4 * 4] = wv;
        }
        __syncthreads();                            // before next Q-tile reuses kb[0]/sc
    }
}

extern "C" void kernel_launch(void* const* d_in, const int* in_sizes, int n_in,
                              void* d_out, int out_size, void* d_ws, size_t ws_size,
                              hipStream_t stream) {
    const float* q = (const float*)d_in[0];
    const float* k = (const float*)d_in[1];
    const float* v = (const float*)d_in[2];
    float* outp  = (float*)d_out;
    float* score = outp + (size_t)4 * 8 * 2048 * 64;     // out first, then score

    unsigned short* Qw  = (unsigned short*)d_ws;          // bf16(2q-1) [bh][n][d]
    unsigned short* Kw  = Qw + (size_t)4 * 8 * 2048 * 64; // bf16(2k-1) [bh][n][d]
    unsigned short* Vtw = Kw + (size_t)4 * 8 * 2048 * 64; // bf16(v)    [bh][d][n]

    prep_qk<<<4096, 256, 0, stream>>>((const float4*)q, (const float4*)k,
                                      (ushort4*)Qw, (ushort4*)Kw);
    prep_v<<<1024, 256, 0, stream>>>(v, Vtw);
    attn<<<512, 256, 0, stream>>>(Qw, Kw, Vtw, outp, score);
}